// Round 6
// baseline (176.107 us; speedup 1.0000x reference)
//
#include <hip/hip_runtime.h>
#include <hip/hip_bf16.h>

typedef __bf16 bf16x8 __attribute__((ext_vector_type(8)));
typedef float  f32x4  __attribute__((ext_vector_type(4)));

// Sizes: q [1024][128] f32, k [1024][128] f32, queue [128][65536] f32,
//        prototypes [1000][128] f32, target [1024] int32
// Outputs (concat f32): logits [1024][65537], logits_proto [1024][1000],
//        new_queue [128][65536], new_prototypes [1000][128]
// d_ws: Bt = bf16 queue^T [65536][128], qbf = bf16(10*q) [1024][128]

#define B_   1024
#define D_   128
#define K_   65536
#define C_   1000
#define LROW 65537
#define TINV 10.0f

// ---- bt_make: queue col-tiles -> bf16 transposed Bt (32KB linear write/block) ----
__global__ __launch_bounds__(256) void bt_make(const float* __restrict__ queue,
                                               __bf16* __restrict__ Bt) {
    __shared__ __bf16 Lt[128 * 128];
    char* ltb = (char*)Lt;
    const int tid = threadIdx.x;
    const int c0  = blockIdx.x * 128;
    #pragma unroll
    for (int it = 0; it < 16; ++it) {
        const int idx = it * 256 + tid;          // float4 slot in 128d x 128c tile
        const int d   = idx >> 5;
        const int cq  = (idx & 31) * 4;
        const float4 v = *reinterpret_cast<const float4*>(queue + (size_t)d * K_ + c0 + cq);
        const int db = d >> 3, de = (d & 7) * 2;
        float vv[4] = {v.x, v.y, v.z, v.w};
        #pragma unroll
        for (int jj = 0; jj < 4; ++jj) {
            const int c = cq + jj;
            *reinterpret_cast<__bf16*>(ltb + c * 256 + ((db ^ ((c >> 2) & 15)) << 4) + de)
                = (__bf16)vv[jj];
        }
    }
    __syncthreads();
    #pragma unroll
    for (int it = 0; it < 8; ++it) {
        const int idx = it * 256 + tid;          // 16B chunk: c = idx>>4, db = idx&15
        const int c   = idx >> 4;
        const int db  = idx & 15;
        const bf16x8 v = *reinterpret_cast<const bf16x8*>(
            ltb + c * 256 + ((db ^ ((c >> 2) & 15)) << 4));
        *reinterpret_cast<bf16x8*>(Bt + (size_t)(c0 + c) * D_ + db * 8) = v;
    }
}

// ---- qcopy_lin: new_queue = queue (linear 64KB spans) with cols<1024 = k^T ----
// grid 512: block b -> d = b>>2, quarter = b&3 (16384 cols each)
__global__ __launch_bounds__(256) void qcopy_lin(const float* __restrict__ queue,
                                                 const float* __restrict__ k,
                                                 float* __restrict__ outq) {
    const int tid = threadIdx.x;
    const int d   = blockIdx.x >> 2;
    const int qt  = blockIdx.x & 3;
    const size_t rowoff = (size_t)d * K_;
    const float4* src = reinterpret_cast<const float4*>(queue + rowoff);
    float4*       dst = reinterpret_cast<float4*>(outq + rowoff);
    if (qt == 0) {
        #pragma unroll
        for (int i = 0; i < 4; ++i) {            // cols 0..1023 from k^T
            const int c = i * 256 + tid;
            outq[rowoff + c] = k[(size_t)c * D_ + d];
        }
        #pragma unroll 4
        for (int i = 0; i < 15; ++i) {           // cols 1024..16383 linear
            const int idx = 256 + i * 256 + tid; // float4 index
            dst[idx] = src[idx];
        }
    } else {
        const int base = qt * 4096;              // float4 index
        #pragma unroll 4
        for (int i = 0; i < 16; ++i) {
            const int idx = base + i * 256 + tid;
            dst[idx] = src[idx];
        }
    }
}

// ---- misc_fused: lpos+qbf | gemm_proto | proto_update, by blockIdx ----
#define MB_LPOS   256
#define MB_PROTO  1008   // (63,16) linearized
#define MB_PUPD   500    // 2 classes per block
__global__ __launch_bounds__(256) void misc_fused(const float* __restrict__ q,
                                                  const float* __restrict__ k,
                                                  const float* __restrict__ protos,
                                                  const int* __restrict__ target,
                                                  float* __restrict__ logits,
                                                  __bf16* __restrict__ qbf,
                                                  float* __restrict__ lproto,
                                                  float* __restrict__ outp) {
    __shared__ int   t[B_];
    __shared__ float red[2][2];
    const int bid = blockIdx.x;
    const int tid = threadIdx.x;

    if (bid < MB_LPOS) {
        // ---- l_pos + qbf ----
        const int wid  = tid >> 6;
        const int lane = tid & 63;
        const int row  = bid * 4 + wid;
        const float2 qv = reinterpret_cast<const float2*>(q + (size_t)row * D_)[lane];
        const float2 kv = reinterpret_cast<const float2*>(k + (size_t)row * D_)[lane];
        union { __bf16 h[2]; unsigned int u; } u2;
        u2.h[0] = (__bf16)(qv.x * TINV);
        u2.h[1] = (__bf16)(qv.y * TINV);
        reinterpret_cast<unsigned int*>(qbf)[row * 64 + lane] = u2.u;
        float p = qv.x * kv.x + qv.y * kv.y;
        #pragma unroll
        for (int off = 32; off > 0; off >>= 1) p += __shfl_xor(p, off);
        if (lane == 0) logits[(size_t)row * LROW] = p * TINV;

    } else if (bid < MB_LPOS + MB_PROTO) {
        // ---- gemm_proto: lproto = (10*q) @ protos^T ----
        const int pid  = bid - MB_LPOS;
        const int bx   = pid % 63, by = pid / 63;
        const int wid  = tid >> 6;
        const int lane = tid & 63;
        const int mrow = (by * 4 + wid) * 16;
        const int ncol = bx * 16;
        const int bl = lane & 15, gk = lane >> 4;
        const int col = ncol + bl;
        const bool valid = (col < C_);

        f32x4 acc = {};
        #pragma unroll
        for (int s = 0; s < 4; ++s) {
            const int koff = s * 32 + gk * 8;
            const float* ap = q + (size_t)(mrow + bl) * D_ + koff;
            bf16x8 a, b;
            #pragma unroll
            for (int v = 0; v < 8; ++v) a[v] = (__bf16)(ap[v] * TINV);
            if (valid) {
                const float* bp = protos + (size_t)col * D_ + koff;
                #pragma unroll
                for (int v = 0; v < 8; ++v) b[v] = (__bf16)bp[v];
            } else {
                #pragma unroll
                for (int v = 0; v < 8; ++v) b[v] = (__bf16)0.0f;
            }
            acc = __builtin_amdgcn_mfma_f32_16x16x32_bf16(a, b, acc, 0, 0, 0);
        }
        #pragma unroll
        for (int r = 0; r < 4; ++r) {
            const int orow = mrow + gk * 4 + r;
            if (valid) lproto[(size_t)orow * C_ + col] = acc[r];
        }

    } else {
        // ---- proto_update: 2 classes per block ----
        const int pid = bid - (MB_LPOS + MB_PROTO);
        const int sub = tid >> 7;          // 0/1
        const int d   = tid & 127;
        const int c   = pid * 2 + sub;     // < 1000
        for (int i = tid; i < B_; i += 256) t[i] = target[i];
        __syncthreads();

        float acc = 0.0f, wgt = 1.0f;
        int cnt = 0;
        for (int i = 0; i < B_; ++i) {
            if (t[i] == c) {                 // wave-uniform (LDS broadcast)
                ++cnt;
                wgt *= 1.0010010010010010f;  // 1/0.999 -> m^(-occ_i)
                acc = fmaf(wgt, q[(size_t)i * D_ + d], acc);
            }
        }
        const float val = powf(0.999f, (float)cnt) *
                          fmaf(0.001f, acc, protos[(size_t)c * D_ + d]);

        float ss = val * val;
        #pragma unroll
        for (int off = 32; off > 0; off >>= 1) ss += __shfl_xor(ss, off);
        if ((d & 63) == 0) red[sub][d >> 6] = ss;
        __syncthreads();
        const float norm = sqrtf(red[sub][0] + red[sub][1]);
        outp[(size_t)c * D_ + d] = val / fmaxf(norm, 1e-12f);
    }
}

// ---- big GEMM: logits[:,1:] = qbf @ Bt^T. Col-fastest within XCD (R2 order):
// in-flight window = narrow row band x wide contiguous cols -> DRAM-friendly writes.
__global__ __launch_bounds__(256) void gemm_neg(const __bf16* __restrict__ qbf,
                                                const __bf16* __restrict__ Bt,
                                                float* __restrict__ logits) {
    __shared__ __bf16 Alds[128][128];            // 16B block cb of row r at cb^(r&7)
    const int tid = threadIdx.x, wid = tid >> 6, lane = tid & 63;
    const int lin = blockIdx.y * 512 + blockIdx.x;
    const int xcd = lin & 7, j = lin >> 3;
    const int bcol = (xcd * 64 + (j & 63)) * 128;   // col-tile fastest within xcd
    const int brow = (j >> 6) * 128;

    #pragma unroll
    for (int it = 0; it < 8; ++it) {
        const int idx = it * 256 + tid;          // 16B-block slot 0..2047
        const int r   = idx >> 4;
        const int cb  = idx & 15;
        const bf16x8 v = *reinterpret_cast<const bf16x8*>(qbf + (size_t)(brow + r) * D_ + cb * 8);
        *reinterpret_cast<bf16x8*>(&Alds[r][(cb ^ (r & 7)) * 8]) = v;
    }
    __syncthreads();

    const int bl = lane & 15, gk = lane >> 4;
    const int colbase = bcol + wid * 32;

    f32x4 acc[8][2] = {};
    #pragma unroll
    for (int s = 0; s < 4; ++s) {
        const int koff = s * 32 + gk * 8;
        bf16x8 af[8];
        #pragma unroll
        for (int m = 0; m < 8; ++m) {
            const int r = m * 16 + bl;
            af[m] = *reinterpret_cast<const bf16x8*>(&Alds[r][((s * 4 + gk) ^ (r & 7)) * 8]);
        }
        #pragma unroll
        for (int n = 0; n < 2; ++n) {
            const bf16x8 bfrag = *reinterpret_cast<const bf16x8*>(
                Bt + (size_t)(colbase + n * 16 + bl) * D_ + koff);
            #pragma unroll
            for (int m = 0; m < 8; ++m)
                acc[m][n] = __builtin_amdgcn_mfma_f32_16x16x32_bf16(af[m], bfrag, acc[m][n], 0, 0, 0);
        }
    }

    // C/D: col = lane&15, row = (lane>>4)*4 + r
    #pragma unroll
    for (int m = 0; m < 8; ++m)
        #pragma unroll
        for (int n = 0; n < 2; ++n)
            #pragma unroll
            for (int r = 0; r < 4; ++r) {
                const int orow = brow + m * 16 + (gk << 2) + r;
                logits[(size_t)orow * LROW + 1 + colbase + n * 16 + bl] = acc[m][n][r];
            }
}

extern "C" void kernel_launch(void* const* d_in, const int* in_sizes, int n_in,
                              void* d_out, int out_size, void* d_ws, size_t ws_size,
                              hipStream_t stream) {
    const float* q      = (const float*)d_in[0];
    const float* k      = (const float*)d_in[1];
    const float* queue  = (const float*)d_in[2];
    const float* protos = (const float*)d_in[3];
    const int*   target = (const int*)d_in[4];

    float* out    = (float*)d_out;
    float* logits = out;                                  // [1024][65537]
    float* lproto = out + (size_t)B_ * LROW;              // [1024][1000]
    float* outq   = lproto + (size_t)B_ * C_;             // [128][65536]
    float* outp   = outq + (size_t)D_ * K_;               // [1000][128]

    __bf16* Bt  = (__bf16*)d_ws;                          // [65536][128]
    __bf16* qbf = (__bf16*)((char*)d_ws + (size_t)K_ * D_ * 2);  // [1024][128]

    bt_make   <<<K_ / 128, 256, 0, stream>>>(queue, Bt);
    misc_fused<<<MB_LPOS + MB_PROTO + MB_PUPD, 256, 0, stream>>>(
        q, k, protos, target, logits, qbf, lproto, outp);
    gemm_neg  <<<dim3(512, 8), 256, 0, stream>>>(qbf, Bt, logits);
    qcopy_lin <<<512, 256, 0, stream>>>(queue, k, outq);
}